// Round 3
// baseline (221.970 us; speedup 1.0000x reference)
//
#include <hip/hip_runtime.h>
#include <hip/hip_bf16.h>

// ---------------- Kernel P: one-time prep: P_node transpose + row norms ----------------
__global__ __launch_bounds__(256) void prep_kernel(
    const float* __restrict__ Pn, float* __restrict__ Pt, float* __restrict__ q)
{
  const int t = threadIdx.x;
  for (int i = t; i < 3072; i += 256) {
    int j = i >> 6, p = i & 63;
    Pt[i] = Pn[p * 48 + j];
  }
  if (t < 64) {
    float s = 0.f;
    #pragma unroll
    for (int j = 0; j < 48; ++j) { float v = Pn[t * 48 + j]; s = fmaf(v, v, s); }
    q[t] = s;
  }
}

// ---------------- Kernel A: node embed + soft-proto + mean ----------------
// one block (512 thr) per (sample, branch). LDS ~50.8 KB -> 3 blocks/CU.
// sS (scores/weights, 90x68) aliases sX (dead after embed).
__global__ __launch_bounds__(512, 6) void node_kernel(
    const float* __restrict__ fcn, const float* __restrict__ scn,
    const float* __restrict__ Wn, const float* __restrict__ bn,
    const float* __restrict__ Pn, const float* __restrict__ Ptg,
    const float* __restrict__ qg,
    float* __restrict__ R, float* __restrict__ nmmean)
{
  __shared__ __align__(16) float sXS[90 * 92];  // x during embed; scores after
  __shared__ __align__(16) float sN[90 * 48];   // nodes, then nm
  __shared__ float sMean[96];
  float* sX = sXS;
  float* sS = sXS;                              // stride 68 view (6120 <= 8280)

  const int tid = threadIdx.x;
  const int b = blockIdx.x, br = blockIdx.y;
  const float* x = (br ? scn : fcn) + (size_t)b * 8100;

  // stage x -> sX [90][92]
  for (int i4 = tid; i4 < 2025; i4 += 512) {
    float4 v = *(const float4*)&x[i4 * 4];
    const float vv[4] = {v.x, v.y, v.z, v.w};
    #pragma unroll
    for (int e = 0; e < 4; ++e) {
      int idx = i4 * 4 + e;
      int r = idx / 90, c = idx - r * 90;
      sX[r * 92 + c] = vv[e];
    }
  }
  __syncthreads();

  // ---- embed: nodes = x @ Wn + bn -> sN[90][48]; 3-row x 4-col tiles ----
  if (tid < 360) {
    const int i3 = tid / 12, j4 = (tid - i3 * 12) * 4;
    const int r0 = i3 * 3, r1 = r0 + 1, r2 = r0 + 2;
    float4 bv = *(const float4*)&bn[j4];
    float a00 = bv.x, a01 = bv.y, a02 = bv.z, a03 = bv.w;
    float a10 = bv.x, a11 = bv.y, a12 = bv.z, a13 = bv.w;
    float a20 = bv.x, a21 = bv.y, a22 = bv.z, a23 = bv.w;
    const float* x0 = &sX[r0 * 92];
    const float* x1 = &sX[r1 * 92];
    const float* x2 = &sX[r2 * 92];
    #pragma unroll 2
    for (int k = 0; k < 88; k += 4) {
      float4 xv0 = *(const float4*)&x0[k];
      float4 xv1 = *(const float4*)&x1[k];
      float4 xv2 = *(const float4*)&x2[k];
      const float f0[4] = {xv0.x, xv0.y, xv0.z, xv0.w};
      const float f1[4] = {xv1.x, xv1.y, xv1.z, xv1.w};
      const float f2[4] = {xv2.x, xv2.y, xv2.z, xv2.w};
      #pragma unroll
      for (int e = 0; e < 4; ++e) {
        float4 wv = *(const float4*)&Wn[(k + e) * 48 + j4];
        a00 = fmaf(f0[e], wv.x, a00); a01 = fmaf(f0[e], wv.y, a01);
        a02 = fmaf(f0[e], wv.z, a02); a03 = fmaf(f0[e], wv.w, a03);
        a10 = fmaf(f1[e], wv.x, a10); a11 = fmaf(f1[e], wv.y, a11);
        a12 = fmaf(f1[e], wv.z, a12); a13 = fmaf(f1[e], wv.w, a13);
        a20 = fmaf(f2[e], wv.x, a20); a21 = fmaf(f2[e], wv.y, a21);
        a22 = fmaf(f2[e], wv.z, a22); a23 = fmaf(f2[e], wv.w, a23);
      }
    }
    #pragma unroll
    for (int k = 88; k < 90; ++k) {
      float xv0 = x0[k], xv1 = x1[k], xv2 = x2[k];
      float4 wv = *(const float4*)&Wn[k * 48 + j4];
      a00 = fmaf(xv0, wv.x, a00); a01 = fmaf(xv0, wv.y, a01);
      a02 = fmaf(xv0, wv.z, a02); a03 = fmaf(xv0, wv.w, a03);
      a10 = fmaf(xv1, wv.x, a10); a11 = fmaf(xv1, wv.y, a11);
      a12 = fmaf(xv1, wv.z, a12); a13 = fmaf(xv1, wv.w, a13);
      a20 = fmaf(xv2, wv.x, a20); a21 = fmaf(xv2, wv.y, a21);
      a22 = fmaf(xv2, wv.z, a22); a23 = fmaf(xv2, wv.w, a23);
    }
    *(float4*)&sN[r0 * 48 + j4] = make_float4(a00, a01, a02, a03);
    *(float4*)&sN[r1 * 48 + j4] = make_float4(a10, a11, a12, a13);
    *(float4*)&sN[r2 * 48 + j4] = make_float4(a20, a21, a22, a23);
  }
  __syncthreads();

  // ---- scores + fused softmax: 16 lanes per row, 4 protos per lane ----
  // s[i][p] = 2*(n_i . P_p) - ||P_p||^2  (softmax-equivalent to -d2)
  for (int v = tid; v < 1440; v += 512) {
    const int row = v >> 4, p4 = (v & 15) * 4;
    const float* nr = &sN[row * 48];
    float s0 = 0.f, s1 = 0.f, s2 = 0.f, s3 = 0.f;
    #pragma unroll 3
    for (int j4 = 0; j4 < 48; j4 += 4) {
      float4 nv = *(const float4*)&nr[j4];
      const float f[4] = {nv.x, nv.y, nv.z, nv.w};
      #pragma unroll
      for (int e = 0; e < 4; ++e) {
        float4 pt = *(const float4*)&Ptg[(j4 + e) * 64 + p4];
        s0 = fmaf(f[e], pt.x, s0); s1 = fmaf(f[e], pt.y, s1);
        s2 = fmaf(f[e], pt.z, s2); s3 = fmaf(f[e], pt.w, s3);
      }
    }
    float4 qv = *(const float4*)&qg[p4];
    s0 = fmaf(2.f, s0, -qv.x); s1 = fmaf(2.f, s1, -qv.y);
    s2 = fmaf(2.f, s2, -qv.z); s3 = fmaf(2.f, s3, -qv.w);
    // 16-lane group softmax (lanes of one row share lane>>4)
    float m = fmaxf(fmaxf(s0, s1), fmaxf(s2, s3));
    m = fmaxf(m, __shfl_xor(m, 1, 64));
    m = fmaxf(m, __shfl_xor(m, 2, 64));
    m = fmaxf(m, __shfl_xor(m, 4, 64));
    m = fmaxf(m, __shfl_xor(m, 8, 64));
    float e0 = __expf(s0 - m), e1 = __expf(s1 - m);
    float e2 = __expf(s2 - m), e3 = __expf(s3 - m);
    float sum = (e0 + e1) + (e2 + e3);
    sum += __shfl_xor(sum, 1, 64);
    sum += __shfl_xor(sum, 2, 64);
    sum += __shfl_xor(sum, 4, 64);
    sum += __shfl_xor(sum, 8, 64);
    float inv = 1.f / sum;
    *(float4*)&sS[row * 68 + p4] =
        make_float4(e0 * inv, e1 * inv, e2 * inv, e3 * inv);
  }
  __syncthreads();

  // ---- nm = w @ P -> R and sN; 3-row x 4-col tiles ----
  float* Rrow = R + (size_t)b * 8736 + (size_t)br * 4320;
  if (tid < 360) {
    const int i3 = tid / 12, j4 = (tid - i3 * 12) * 4;
    const int r0 = i3 * 3, r1 = r0 + 1, r2 = r0 + 2;
    float a00 = 0, a01 = 0, a02 = 0, a03 = 0;
    float a10 = 0, a11 = 0, a12 = 0, a13 = 0;
    float a20 = 0, a21 = 0, a22 = 0, a23 = 0;
    const float* w0 = &sS[r0 * 68];
    const float* w1 = &sS[r1 * 68];
    const float* w2 = &sS[r2 * 68];
    #pragma unroll 2
    for (int p4 = 0; p4 < 64; p4 += 4) {
      float4 wv0 = *(const float4*)&w0[p4];
      float4 wv1 = *(const float4*)&w1[p4];
      float4 wv2 = *(const float4*)&w2[p4];
      const float f0[4] = {wv0.x, wv0.y, wv0.z, wv0.w};
      const float f1[4] = {wv1.x, wv1.y, wv1.z, wv1.w};
      const float f2[4] = {wv2.x, wv2.y, wv2.z, wv2.w};
      #pragma unroll
      for (int e = 0; e < 4; ++e) {
        float4 pv = *(const float4*)&Pn[(p4 + e) * 48 + j4];
        a00 = fmaf(f0[e], pv.x, a00); a01 = fmaf(f0[e], pv.y, a01);
        a02 = fmaf(f0[e], pv.z, a02); a03 = fmaf(f0[e], pv.w, a03);
        a10 = fmaf(f1[e], pv.x, a10); a11 = fmaf(f1[e], pv.y, a11);
        a12 = fmaf(f1[e], pv.z, a12); a13 = fmaf(f1[e], pv.w, a13);
        a20 = fmaf(f2[e], pv.x, a20); a21 = fmaf(f2[e], pv.y, a21);
        a22 = fmaf(f2[e], pv.z, a22); a23 = fmaf(f2[e], pv.w, a23);
      }
    }
    *(float4*)&sN[r0 * 48 + j4] = make_float4(a00, a01, a02, a03);
    *(float4*)&sN[r1 * 48 + j4] = make_float4(a10, a11, a12, a13);
    *(float4*)&sN[r2 * 48 + j4] = make_float4(a20, a21, a22, a23);
    *(float4*)&Rrow[r0 * 48 + j4] = make_float4(a00, a01, a02, a03);
    *(float4*)&Rrow[r1 * 48 + j4] = make_float4(a10, a11, a12, a13);
    *(float4*)&Rrow[r2 * 48 + j4] = make_float4(a20, a21, a22, a23);
  }
  __syncthreads();

  if (tid < 96) {
    int j = tid < 48 ? tid : tid - 48;
    int h = tid < 48 ? 0 : 1;
    float s = 0.f;
    for (int i = h * 45; i < h * 45 + 45; ++i) s += sN[i * 48 + j];
    sMean[tid] = s;
  }
  __syncthreads();
  if (tid < 48) {
    nmmean[((size_t)br * 1024 + b) * 48 + tid] =
        (sMean[tid] + sMean[48 + tid]) * (1.f / 90.f);
  }
}

// ---------------- Kernel B: graph-level tiny MLPs + soft-protos ----------------
__global__ __launch_bounds__(256) void graph_kernel(
    const float* __restrict__ nmmean,
    const float* __restrict__ Wg, const float* __restrict__ bg,
    const float* __restrict__ Pg,
    const float* __restrict__ Wg1, const float* __restrict__ bg1,
    const float* __restrict__ Wg2, const float* __restrict__ bg2,
    const float* __restrict__ Pc,
    float* __restrict__ R)
{
  __shared__ float sE[4][64];
  __shared__ float sT[4][64];
  const int tid = threadIdx.x;
  const int wid = tid >> 6, lane = tid & 63;
  const int idx = blockIdx.x * 4 + wid;
  const int br = idx >> 10, b = idx & 1023;
  const float* mrow = nmmean + (size_t)idx * 48;
  float* Rrow = R + (size_t)b * 8736;

  if (lane < 32) {
    float e = bg[lane];
    #pragma unroll
    for (int k = 0; k < 48; ++k) e = fmaf(mrow[k], Wg[k * 32 + lane], e);
    sE[wid][lane] = e;
  }
  __syncthreads();
  if (lane < 32) {
    float s = 0.f;
    #pragma unroll
    for (int j = 0; j < 32; ++j) { float pv = Pg[lane * 32 + j]; s += pv * (2.f * sE[wid][j] - pv); }
    float m = s;
    for (int d = 16; d >= 1; d >>= 1) m = fmaxf(m, __shfl_xor(m, d, 64));
    float ex = __expf(s - m);
    float sum = ex;
    for (int d = 16; d >= 1; d >>= 1) sum += __shfl_xor(sum, d, 64);
    sT[wid][lane] = ex / sum;
  }
  __syncthreads();
  if (lane < 32) {
    float g = 0.f;
    #pragma unroll
    for (int p = 0; p < 32; ++p) g = fmaf(sT[wid][p], Pg[p * 32 + lane], g);
    Rrow[8640 + br * 32 + lane] = g;
    sE[wid][lane] = g;
  }
  __syncthreads();
  if (lane < 32) {
    float h = bg1[lane];
    #pragma unroll
    for (int k = 0; k < 32; ++k) h = fmaf(sE[wid][k], Wg1[k * 32 + lane], h);
    sT[wid][lane] = fmaxf(h, 0.f);
  }
  __syncthreads();
  if (lane < 16) {
    float c = bg2[lane];
    #pragma unroll
    for (int k = 0; k < 32; ++k) c = fmaf(sT[wid][k], Wg2[k * 16 + lane], c);
    sE[wid][lane] = c;
  }
  __syncthreads();
  if (lane < 16) {
    float s = 0.f;
    #pragma unroll
    for (int j = 0; j < 16; ++j) { float pv = Pc[lane * 16 + j]; s += pv * (2.f * sE[wid][j] - pv); }
    float m = s;
    for (int d = 8; d >= 1; d >>= 1) m = fmaxf(m, __shfl_xor(m, d, 64));
    float ex = __expf(s - m);
    float sum = ex;
    for (int d = 8; d >= 1; d >>= 1) sum += __shfl_xor(sum, d, 64);
    sT[wid][lane] = ex / sum;
  }
  __syncthreads();
  if (lane < 16) {
    float c = 0.f;
    #pragma unroll
    for (int p = 0; p < 16; ++p) c = fmaf(sT[wid][p], Pc[p * 16 + lane], c);
    Rrow[8704 + br * 16 + lane] = c;
  }
}

// ---------------- Kernel C: split-K fp32 GEMM with register prefetch ----------------
// M=1024, N=256, K=8736 (273 tiles of BK=32). KS chunks, runtime.
__global__ __launch_bounds__(256) void gemm1_kernel(
    const float* __restrict__ R, const float* __restrict__ Wc1,
    float* __restrict__ part, int KS)
{
  __shared__ __align__(16) float sA[32 * 68];
  __shared__ __align__(16) float sBt[32 * 68];
  const int tid = threadIdx.x;
  const int bm = blockIdx.x * 64, bnc = blockIdx.y * 64, z = blockIdx.z;
  const int base = 273 / KS, rem = 273 - base * KS;
  const int t0 = z * base + (z < rem ? z : rem);
  const int nt = base + (z < rem ? 1 : 0);
  const int kbeg = t0 * 32, kend = (t0 + nt) * 32;
  const int tx = tid & 15, ty = tid >> 4;
  const int la_k = tid & 31, la_r = tid >> 5;
  const int lb_c = tid & 63, lb_k = tid >> 6;
  float acc[4][4] = {{0.f}};
  float ra[8], rb[8];

  // prefetch first tile into registers
  #pragma unroll
  for (int r = 0; r < 8; ++r)
    ra[r] = R[(size_t)(bm + la_r + r * 8) * 8736 + kbeg + la_k];
  #pragma unroll
  for (int k = 0; k < 8; ++k)
    rb[k] = Wc1[(size_t)(kbeg + lb_k + k * 4) * 256 + bnc + lb_c];

  for (int kk = kbeg; kk < kend; kk += 32) {
    #pragma unroll
    for (int r = 0; r < 8; ++r) sA[la_k * 68 + la_r + r * 8] = ra[r];
    #pragma unroll
    for (int k = 0; k < 8; ++k) sBt[(lb_k + k * 4) * 68 + lb_c] = rb[k];
    __syncthreads();
    if (kk + 32 < kend) {
      #pragma unroll
      for (int r = 0; r < 8; ++r)
        ra[r] = R[(size_t)(bm + la_r + r * 8) * 8736 + kk + 32 + la_k];
      #pragma unroll
      for (int k = 0; k < 8; ++k)
        rb[k] = Wc1[(size_t)(kk + 32 + lb_k + k * 4) * 256 + bnc + lb_c];
    }
    #pragma unroll
    for (int k = 0; k < 32; ++k) {
      float4 av = *(const float4*)&sA[k * 68 + ty * 4];
      float4 bv = *(const float4*)&sBt[k * 68 + tx * 4];
      acc[0][0] = fmaf(av.x, bv.x, acc[0][0]);
      acc[0][1] = fmaf(av.x, bv.y, acc[0][1]);
      acc[0][2] = fmaf(av.x, bv.z, acc[0][2]);
      acc[0][3] = fmaf(av.x, bv.w, acc[0][3]);
      acc[1][0] = fmaf(av.y, bv.x, acc[1][0]);
      acc[1][1] = fmaf(av.y, bv.y, acc[1][1]);
      acc[1][2] = fmaf(av.y, bv.z, acc[1][2]);
      acc[1][3] = fmaf(av.y, bv.w, acc[1][3]);
      acc[2][0] = fmaf(av.z, bv.x, acc[2][0]);
      acc[2][1] = fmaf(av.z, bv.y, acc[2][1]);
      acc[2][2] = fmaf(av.z, bv.z, acc[2][2]);
      acc[2][3] = fmaf(av.z, bv.w, acc[2][3]);
      acc[3][0] = fmaf(av.w, bv.x, acc[3][0]);
      acc[3][1] = fmaf(av.w, bv.y, acc[3][1]);
      acc[3][2] = fmaf(av.w, bv.z, acc[3][2]);
      acc[3][3] = fmaf(av.w, bv.w, acc[3][3]);
    }
    __syncthreads();
  }
  float* pz = part + (size_t)z * 262144;
  #pragma unroll
  for (int m = 0; m < 4; ++m) {
    *(float4*)&pz[(size_t)(bm + ty * 4 + m) * 256 + bnc + tx * 4] =
        make_float4(acc[m][0], acc[m][1], acc[m][2], acc[m][3]);
  }
}

// ---------------- Kernel D: reduce K-partials + relu + [256->3] head ----------------
__global__ __launch_bounds__(256) void head_kernel(
    const float* __restrict__ part, const float* __restrict__ bc1,
    const float* __restrict__ Wc2, const float* __restrict__ bc2,
    float* __restrict__ out, int KS)
{
  __shared__ float red[3][4];
  const int b = blockIdx.x, t = threadIdx.x;
  float acc = bc1[t];
  for (int z = 0; z < KS; ++z) acc += part[(size_t)z * 262144 + (size_t)b * 256 + t];
  float h = fmaxf(acc, 0.f);
  float p0 = h * Wc2[t * 3 + 0];
  float p1 = h * Wc2[t * 3 + 1];
  float p2 = h * Wc2[t * 3 + 2];
  for (int d = 32; d >= 1; d >>= 1) {
    p0 += __shfl_xor(p0, d, 64);
    p1 += __shfl_xor(p1, d, 64);
    p2 += __shfl_xor(p2, d, 64);
  }
  const int wid = t >> 6, lane = t & 63;
  if (lane == 0) { red[0][wid] = p0; red[1][wid] = p1; red[2][wid] = p2; }
  __syncthreads();
  if (t < 3) {
    out[(size_t)b * 3 + t] = red[t][0] + red[t][1] + red[t][2] + red[t][3] + bc2[t];
  }
}

extern "C" void kernel_launch(void* const* d_in, const int* in_sizes, int n_in,
                              void* d_out, int out_size, void* d_ws, size_t ws_size,
                              hipStream_t stream) {
  const float* fcn     = (const float*)d_in[0];
  const float* scn     = (const float*)d_in[1];
  const float* W_node  = (const float*)d_in[2];
  const float* b_node  = (const float*)d_in[3];
  const float* P_node  = (const float*)d_in[4];
  const float* W_graph = (const float*)d_in[5];
  const float* b_graph = (const float*)d_in[6];
  const float* P_graph = (const float*)d_in[7];
  const float* Wg1     = (const float*)d_in[8];
  const float* bg1     = (const float*)d_in[9];
  const float* Wg2     = (const float*)d_in[10];
  const float* bg2     = (const float*)d_in[11];
  const float* P_cls   = (const float*)d_in[12];
  const float* Wc1     = (const float*)d_in[13];
  const float* bc1     = (const float*)d_in[14];
  const float* Wc2     = (const float*)d_in[15];
  const float* bc2     = (const float*)d_in[16];
  float* out = (float*)d_out;

  float* ws = (float*)d_ws;
  float* R      = ws;                                // 8,945,664 floats
  float* nmmean = R + 8945664;                       //    98,304
  float* Pt     = nmmean + 98304;                    //     3,072
  float* q      = Pt + 3072;                         //        64
  float* part   = q + 64;                            // KS * 262,144

  const size_t fixed = 8945664 + 98304 + 3072 + 64;
  size_t avail = ws_size / 4 > fixed ? ws_size / 4 - fixed : 0;
  int KS = (int)(avail / 262144);
  if (KS > 8) KS = 8;
  if (KS < 1) KS = 1;

  prep_kernel<<<1, 256, 0, stream>>>(P_node, Pt, q);
  node_kernel<<<dim3(1024, 2), 512, 0, stream>>>(fcn, scn, W_node, b_node,
                                                 P_node, Pt, q, R, nmmean);
  graph_kernel<<<512, 256, 0, stream>>>(nmmean, W_graph, b_graph, P_graph,
                                        Wg1, bg1, Wg2, bg2, P_cls, R);
  gemm1_kernel<<<dim3(16, 4, KS), 256, 0, stream>>>(R, Wc1, part, KS);
  head_kernel<<<1024, 256, 0, stream>>>(part, bc1, Wc2, bc2, out, KS);
}

// Round 6
// 88.954 us; speedup vs baseline: 2.4953x; 2.4953x over previous
//
#include <hip/hip_runtime.h>
#include <hip/hip_bf16.h>

using f16   = _Float16;
using f16x4 = __attribute__((ext_vector_type(4))) _Float16;
using f16x8 = __attribute__((ext_vector_type(8))) _Float16;
using f32x4 = __attribute__((ext_vector_type(4))) float;

// ---------------- Kernel P: Wc1 [8736][256] f32 -> Wc1T [256][8736] f16 ----------------
__global__ __launch_bounds__(256) void wc1t_kernel(
    const float* __restrict__ Wc1, f16* __restrict__ Wc1T)
{
  __shared__ f16 sT[32 * 36];
  const int tid = threadIdx.x;
  const int kt = blockIdx.x, ct = blockIdx.y;      // 273 x 8 tiles of 32x32
  const int c = tid & 31, r4 = (tid >> 5) * 4;
  #pragma unroll
  for (int i = 0; i < 4; ++i) {
    int r = r4 + i;
    sT[c * 36 + r] = (f16)Wc1[(size_t)(kt * 32 + r) * 256 + ct * 32 + c];
  }
  __syncthreads();
  #pragma unroll
  for (int i = 0; i < 4; ++i) {
    int r = r4 + i;
    Wc1T[(size_t)(ct * 32 + r) * 8736 + kt * 32 + c] = sT[r * 36 + c];
  }
}

// ---------------- Kernel A: node embed + soft-proto + mean (f16 MFMA) ----------------
// one block (256 thr, 4 waves) per (sample, branch). LDS ~49 KB -> 3 blocks/CU.
// Planes: A-operand [row][K] ; B-operand [col][K]. MFMA 16x16x32 f16 (+16x16x16 tail).
__global__ __launch_bounds__(256) void node_kernel(
    const float* __restrict__ fcn, const float* __restrict__ scn,
    const float* __restrict__ Wn, const float* __restrict__ bn,
    const float* __restrict__ Pn,
    f16* __restrict__ R, float* __restrict__ nmmean)
{
  __shared__ __align__(16) f16 uR[10368];          // x [96][104] during ph1; later w+PnT
  __shared__ __align__(16) f16 sWnT[48 * 104];     // B of ph1: [n][k]
  __shared__ __align__(16) f16 sNodes[96 * 56];    // A of ph2: [row][j]
  __shared__ __align__(16) f16 sP[64 * 56];        // B of ph2: [p][j] (= Pn rows)
  __shared__ float sQ[64];

  f16* sX   = uR;                 // [96][104]
  f16* sW   = uR;                 // [96][72]  (x dead by then)
  f16* sPnT = uR + 96 * 72;       // [48][72]  (j-major, k=p)

  const int tid = threadIdx.x;
  const int lane = tid & 63, wv = tid >> 6;
  const int l15 = lane & 15, lg = lane >> 4;
  const int b = blockIdx.x, br = blockIdx.y;

  // ---- zero x-region + WnT (k-pad correctness: cols 90..95 must be 0) ----
  for (int i = tid; i < 1296; i += 256) ((float4*)uR)[i] = make_float4(0.f, 0.f, 0.f, 0.f);
  for (int i = tid; i < 624; i += 256) ((float4*)sWnT)[i] = make_float4(0.f, 0.f, 0.f, 0.f);
  __syncthreads();

  // ---- stage x (f32->f16), WnT, P, q ----
  const float* x = (br ? scn : fcn) + (size_t)b * 8100;
  for (int i = tid; i < 2025; i += 256) {
    float4 v = *(const float4*)&x[i * 4];
    const float vv[4] = {v.x, v.y, v.z, v.w};
    #pragma unroll
    for (int e = 0; e < 4; ++e) {
      int idx = i * 4 + e;
      int r = idx / 90, c = idx - 90 * r;
      sX[r * 104 + c] = (f16)vv[e];
    }
  }
  for (int i = tid; i < 4320; i += 256) {
    int k = i / 48, n = i - 48 * k;
    sWnT[n * 104 + k] = (f16)Wn[i];
  }
  for (int i = tid; i < 3072; i += 256) sP[(i / 48) * 56 + (i % 48)] = (f16)Pn[i];
  if (tid < 64) {
    float s = 0.f;
    #pragma unroll
    for (int j = 0; j < 48; ++j) { float v = Pn[tid * 48 + j]; s = fmaf(v, v, s); }
    sQ[tid] = s;
  }
  __syncthreads();

  // ---- ph1: nodes = x @ Wn + bn  (M=96,K=96,N=48) ----
  for (int t = wv; t < 18; t += 4) {
    const int mt = t / 3, nt = t - 3 * mt;
    f32x4 acc = {0.f, 0.f, 0.f, 0.f};
    #pragma unroll
    for (int kt = 0; kt < 3; ++kt) {
      f16x8 a  = *(const f16x8*)&sX[(mt * 16 + l15) * 104 + kt * 32 + lg * 8];
      f16x8 bb = *(const f16x8*)&sWnT[(nt * 16 + l15) * 104 + kt * 32 + lg * 8];
      acc = __builtin_amdgcn_mfma_f32_16x16x32_f16(a, bb, acc, 0, 0, 0);
    }
    const float bias = bn[nt * 16 + l15];
    #pragma unroll
    for (int r = 0; r < 4; ++r)
      sNodes[(mt * 16 + lg * 4 + r) * 56 + nt * 16 + l15] = (f16)(acc[r] + bias);
  }
  __syncthreads();

  // ---- ph2: scores = 2*(nodes @ P^T) - q ; fused row softmax -> w [96][72] ----
  for (int mt = wv; mt < 6; mt += 4) {
    f32x4 acc[4];
    #pragma unroll
    for (int nt = 0; nt < 4; ++nt) acc[nt] = (f32x4){0.f, 0.f, 0.f, 0.f};
    const f16x8 a0 = *(const f16x8*)&sNodes[(mt * 16 + l15) * 56 + lg * 8];
    const f16x4 a1 = *(const f16x4*)&sNodes[(mt * 16 + l15) * 56 + 32 + lg * 4];
    #pragma unroll
    for (int nt = 0; nt < 4; ++nt) {
      f16x8 b0 = *(const f16x8*)&sP[(nt * 16 + l15) * 56 + lg * 8];
      acc[nt] = __builtin_amdgcn_mfma_f32_16x16x32_f16(a0, b0, acc[nt], 0, 0, 0);
      f16x4 b1 = *(const f16x4*)&sP[(nt * 16 + l15) * 56 + 32 + lg * 4];
      acc[nt] = __builtin_amdgcn_mfma_f32_16x16x16f16(a1, b1, acc[nt], 0, 0, 0);
    }
    float qv[4];
    #pragma unroll
    for (int nt = 0; nt < 4; ++nt) qv[nt] = sQ[nt * 16 + l15];
    #pragma unroll
    for (int r = 0; r < 4; ++r) {
      float s0 = 2.f * acc[0][r] - qv[0];
      float s1 = 2.f * acc[1][r] - qv[1];
      float s2 = 2.f * acc[2][r] - qv[2];
      float s3 = 2.f * acc[3][r] - qv[3];
      float m = fmaxf(fmaxf(s0, s1), fmaxf(s2, s3));
      m = fmaxf(m, __shfl_xor(m, 1, 64));
      m = fmaxf(m, __shfl_xor(m, 2, 64));
      m = fmaxf(m, __shfl_xor(m, 4, 64));
      m = fmaxf(m, __shfl_xor(m, 8, 64));
      float e0 = __expf(s0 - m), e1 = __expf(s1 - m);
      float e2 = __expf(s2 - m), e3 = __expf(s3 - m);
      float sum = (e0 + e1) + (e2 + e3);
      sum += __shfl_xor(sum, 1, 64);
      sum += __shfl_xor(sum, 2, 64);
      sum += __shfl_xor(sum, 4, 64);
      sum += __shfl_xor(sum, 8, 64);
      const float inv = 1.f / sum;
      const int row = mt * 16 + lg * 4 + r;
      sW[row * 72 + 0 * 16 + l15] = (f16)(e0 * inv);
      sW[row * 72 + 1 * 16 + l15] = (f16)(e1 * inv);
      sW[row * 72 + 2 * 16 + l15] = (f16)(e2 * inv);
      sW[row * 72 + 3 * 16 + l15] = (f16)(e3 * inv);
    }
  }
  // stage PnT [j][p] into upper union region (x is dead; disjoint from w)
  for (int i = tid; i < 3072; i += 256) {
    int j = i >> 6, p = i & 63;
    sPnT[j * 72 + p] = (f16)Pn[p * 48 + j];
  }
  __syncthreads();

  // ---- ph3: nm = w @ Pn (M=96,K=64,N=48) -> R(f16) + nm back into sNodes for mean ----
  f16* Rrow = R + (size_t)b * 8736 + (size_t)br * 4320;
  for (int t = wv; t < 18; t += 4) {
    const int mt = t / 3, nt = t - 3 * mt;
    f32x4 acc = {0.f, 0.f, 0.f, 0.f};
    #pragma unroll
    for (int kt = 0; kt < 2; ++kt) {
      f16x8 a  = *(const f16x8*)&sW[(mt * 16 + l15) * 72 + kt * 32 + lg * 8];
      f16x8 bb = *(const f16x8*)&sPnT[(nt * 16 + l15) * 72 + kt * 32 + lg * 8];
      acc = __builtin_amdgcn_mfma_f32_16x16x32_f16(a, bb, acc, 0, 0, 0);
    }
    #pragma unroll
    for (int r = 0; r < 4; ++r) {
      const int row = mt * 16 + lg * 4 + r;
      const f16 hv = (f16)acc[r];
      sNodes[row * 56 + nt * 16 + l15] = hv;          // reuse as nm buffer
      if (row < 90) Rrow[row * 48 + nt * 16 + l15] = hv;
    }
  }
  __syncthreads();

  // ---- deterministic column mean over 90 rows ----
  if (tid < 48) {
    float s = 0.f;
    for (int i = 0; i < 90; ++i) s += (float)sNodes[i * 56 + tid];
    nmmean[((size_t)br * 1024 + b) * 48 + tid] = s * (1.f / 90.f);
  }
}

// ---------------- Kernel B: graph-level tiny MLPs + soft-protos ----------------
__global__ __launch_bounds__(256) void graph_kernel(
    const float* __restrict__ nmmean,
    const float* __restrict__ Wg, const float* __restrict__ bg,
    const float* __restrict__ Pg,
    const float* __restrict__ Wg1, const float* __restrict__ bg1,
    const float* __restrict__ Wg2, const float* __restrict__ bg2,
    const float* __restrict__ Pc,
    f16* __restrict__ R)
{
  __shared__ float sE[4][64];
  __shared__ float sT[4][64];
  const int tid = threadIdx.x;
  const int wid = tid >> 6, lane = tid & 63;
  const int idx = blockIdx.x * 4 + wid;
  const int br = idx >> 10, b = idx & 1023;
  const float* mrow = nmmean + (size_t)idx * 48;
  f16* Rrow = R + (size_t)b * 8736;

  if (lane < 32) {
    float e = bg[lane];
    #pragma unroll
    for (int k = 0; k < 48; ++k) e = fmaf(mrow[k], Wg[k * 32 + lane], e);
    sE[wid][lane] = e;
  }
  __syncthreads();
  if (lane < 32) {
    float s = 0.f;
    #pragma unroll
    for (int j = 0; j < 32; ++j) { float pv = Pg[lane * 32 + j]; s += pv * (2.f * sE[wid][j] - pv); }
    float m = s;
    for (int d = 16; d >= 1; d >>= 1) m = fmaxf(m, __shfl_xor(m, d, 64));
    float ex = __expf(s - m);
    float sum = ex;
    for (int d = 16; d >= 1; d >>= 1) sum += __shfl_xor(sum, d, 64);
    sT[wid][lane] = ex / sum;
  }
  __syncthreads();
  if (lane < 32) {
    float g = 0.f;
    #pragma unroll
    for (int p = 0; p < 32; ++p) g = fmaf(sT[wid][p], Pg[p * 32 + lane], g);
    Rrow[8640 + br * 32 + lane] = (f16)g;
    sE[wid][lane] = g;
  }
  __syncthreads();
  if (lane < 32) {
    float h = bg1[lane];
    #pragma unroll
    for (int k = 0; k < 32; ++k) h = fmaf(sE[wid][k], Wg1[k * 32 + lane], h);
    sT[wid][lane] = fmaxf(h, 0.f);
  }
  __syncthreads();
  if (lane < 16) {
    float c = bg2[lane];
    #pragma unroll
    for (int k = 0; k < 32; ++k) c = fmaf(sT[wid][k], Wg2[k * 16 + lane], c);
    sE[wid][lane] = c;
  }
  __syncthreads();
  if (lane < 16) {
    float s = 0.f;
    #pragma unroll
    for (int j = 0; j < 16; ++j) { float pv = Pc[lane * 16 + j]; s += pv * (2.f * sE[wid][j] - pv); }
    float m = s;
    for (int d = 8; d >= 1; d >>= 1) m = fmaxf(m, __shfl_xor(m, d, 64));
    float ex = __expf(s - m);
    float sum = ex;
    for (int d = 8; d >= 1; d >>= 1) sum += __shfl_xor(sum, d, 64);
    sT[wid][lane] = ex / sum;
  }
  __syncthreads();
  if (lane < 16) {
    float c = 0.f;
    #pragma unroll
    for (int p = 0; p < 16; ++p) c = fmaf(sT[wid][p], Pc[p * 16 + lane], c);
    Rrow[8704 + br * 16 + lane] = (f16)c;
  }
}

// ---------------- Kernel C: split-K f16-MFMA GEMM  part_z = R_z @ Wc1_z ----------------
// M=1024 N=256 K=8736 (273 BK=32 tiles). BM=128, BN=64. 4 waves: 2x2.
__global__ __launch_bounds__(256) void gemm1_kernel(
    const f16* __restrict__ R, const f16* __restrict__ Wc1T,
    float* __restrict__ part, int KS)
{
  __shared__ __align__(16) f16 sA[128 * 40];
  __shared__ __align__(16) f16 sB[64 * 40];
  const int tid = threadIdx.x;
  const int lane = tid & 63, wv = tid >> 6;
  const int l15 = lane & 15, lg = lane >> 4;
  const int wm = wv >> 1, wn = wv & 1;
  const int bm = blockIdx.x * 128, bnc = blockIdx.y * 64, z = blockIdx.z;
  const int base = 273 / KS, rem = 273 - base * KS;
  const int t0 = z * base + (z < rem ? z : rem);
  const int nt_ = base + (z < rem ? 1 : 0);
  const int kbeg = t0 * 32, kend = (t0 + nt_) * 32;

  const int ar = tid >> 1, ah = (tid & 1) * 16;   // A staging: row, k-half
  const int bc = tid >> 2, bh = (tid & 3) * 8;    // B staging: col, k-eighth

  f32x4 acc[4][2];
  #pragma unroll
  for (int mt = 0; mt < 4; ++mt)
    #pragma unroll
    for (int nt = 0; nt < 2; ++nt) acc[mt][nt] = (f32x4){0.f, 0.f, 0.f, 0.f};

  for (int kk = kbeg; kk < kend; kk += 32) {
    const f16* asrc = &R[(size_t)(bm + ar) * 8736 + kk + ah];
    f16x8 v0 = *(const f16x8*)asrc;
    f16x8 v1 = *(const f16x8*)(asrc + 8);
    f16x8 w0 = *(const f16x8*)&Wc1T[(size_t)(bnc + bc) * 8736 + kk + bh];
    *(f16x8*)&sA[ar * 40 + ah] = v0;
    *(f16x8*)&sA[ar * 40 + ah + 8] = v1;
    *(f16x8*)&sB[bc * 40 + bh] = w0;
    __syncthreads();
    #pragma unroll
    for (int mt = 0; mt < 4; ++mt) {
      f16x8 a = *(const f16x8*)&sA[(wm * 64 + mt * 16 + l15) * 40 + lg * 8];
      #pragma unroll
      for (int nt = 0; nt < 2; ++nt) {
        f16x8 bb = *(const f16x8*)&sB[(wn * 32 + nt * 16 + l15) * 40 + lg * 8];
        acc[mt][nt] = __builtin_amdgcn_mfma_f32_16x16x32_f16(a, bb, acc[mt][nt], 0, 0, 0);
      }
    }
    __syncthreads();
  }
  float* pz = part + (size_t)z * 262144;
  #pragma unroll
  for (int mt = 0; mt < 4; ++mt)
    #pragma unroll
    for (int nt = 0; nt < 2; ++nt)
      #pragma unroll
      for (int r = 0; r < 4; ++r)
        pz[(size_t)(bm + wm * 64 + mt * 16 + lg * 4 + r) * 256 +
           bnc + wn * 32 + nt * 16 + l15] = acc[mt][nt][r];
}

// ---------------- Kernel D: reduce K-partials + relu + [256->3] head ----------------
__global__ __launch_bounds__(256) void head_kernel(
    const float* __restrict__ part, const float* __restrict__ bc1,
    const float* __restrict__ Wc2, const float* __restrict__ bc2,
    float* __restrict__ out, int KS)
{
  __shared__ float red[3][4];
  const int b = blockIdx.x, t = threadIdx.x;
  float acc = bc1[t];
  for (int z = 0; z < KS; ++z) acc += part[(size_t)z * 262144 + (size_t)b * 256 + t];
  float h = fmaxf(acc, 0.f);
  float p0 = h * Wc2[t * 3 + 0];
  float p1 = h * Wc2[t * 3 + 1];
  float p2 = h * Wc2[t * 3 + 2];
  for (int d = 32; d >= 1; d >>= 1) {
    p0 += __shfl_xor(p0, d, 64);
    p1 += __shfl_xor(p1, d, 64);
    p2 += __shfl_xor(p2, d, 64);
  }
  const int wid = t >> 6, lane = t & 63;
  if (lane == 0) { red[0][wid] = p0; red[1][wid] = p1; red[2][wid] = p2; }
  __syncthreads();
  if (t < 3) {
    out[(size_t)b * 3 + t] = red[t][0] + red[t][1] + red[t][2] + red[t][3] + bc2[t];
  }
}

extern "C" void kernel_launch(void* const* d_in, const int* in_sizes, int n_in,
                              void* d_out, int out_size, void* d_ws, size_t ws_size,
                              hipStream_t stream) {
  const float* fcn     = (const float*)d_in[0];
  const float* scn     = (const float*)d_in[1];
  const float* W_node  = (const float*)d_in[2];
  const float* b_node  = (const float*)d_in[3];
  const float* P_node  = (const float*)d_in[4];
  const float* W_graph = (const float*)d_in[5];
  const float* b_graph = (const float*)d_in[6];
  const float* P_graph = (const float*)d_in[7];
  const float* Wg1     = (const float*)d_in[8];
  const float* bg1     = (const float*)d_in[9];
  const float* Wg2     = (const float*)d_in[10];
  const float* bg2     = (const float*)d_in[11];
  const float* P_cls   = (const float*)d_in[12];
  const float* Wc1     = (const float*)d_in[13];
  const float* bc1     = (const float*)d_in[14];
  const float* Wc2     = (const float*)d_in[15];
  const float* bc2     = (const float*)d_in[16];
  float* out = (float*)d_out;

  char* ws = (char*)d_ws;
  f16*   R16    = (f16*)ws;                              // 8,945,664 f16 = 17,891,328 B
  f16*   Wc1T   = (f16*)(ws + 17891328);                 // 2,236,416 f16 =  4,472,832 B
  float* nmmean = (float*)(ws + 17891328 + 4472832);     //    98,304 f32 =    393,216 B
  float* part   = (float*)(ws + 17891328 + 4472832 + 393216);

  const size_t fixed = 17891328u + 4472832u + 393216u;
  size_t avail = ws_size > fixed ? ws_size - fixed : 0;
  int KS = (int)(avail / (262144 * 4));
  if (KS > 16) KS = 16;
  if (KS < 1) KS = 1;

  wc1t_kernel<<<dim3(273, 8), 256, 0, stream>>>(Wc1, Wc1T);
  node_kernel<<<dim3(1024, 2), 256, 0, stream>>>(fcn, scn, W_node, b_node,
                                                 P_node, R16, nmmean);
  graph_kernel<<<512, 256, 0, stream>>>(nmmean, W_graph, b_graph, P_graph,
                                        Wg1, bg1, Wg2, bg2, P_cls, R16);
  gemm1_kernel<<<dim3(8, 4, KS), 256, 0, stream>>>(R16, Wc1T, part, KS);
  head_kernel<<<1024, 256, 0, stream>>>(part, bc1, Wc2, bc2, out, KS);
}